// Round 4
// baseline (123.645 us; speedup 1.0000x reference)
//
#include <hip/hip_runtime.h>
#include <math.h>

typedef __attribute__((ext_vector_type(8))) short bf16x8;
typedef __attribute__((ext_vector_type(16))) float fx16;

#define SEQ 2048
#define HD 64

// ---------- helpers ----------
__device__ __forceinline__ unsigned f2bf_bits(float f){
  unsigned u = __float_as_uint(f);
  return (u + 0x7fffu + ((u >> 16) & 1u)) >> 16;   // RNE to bf16
}
__device__ __forceinline__ unsigned cvt_pk_bf16(float a, float b){
  unsigned r;
  asm("v_cvt_pk_bf16_f32 %0, %1, %2" : "=v"(r) : "v"(a), "v"(b));
  return r;  // [15:0]=bf16(a), [31:16]=bf16(b)
}
union U8 { bf16x8 v; short s[8]; unsigned u[4]; };

__device__ __forceinline__ fx16 mfma_bf16(bf16x8 a, bf16x8 b, fx16 c){
  return __builtin_amdgcn_mfma_f32_32x32x16_bf16(a, b, c, 0, 0, 0);
}
__device__ __forceinline__ fx16 fzero(){
  fx16 z;
#pragma unroll
  for (int i = 0; i < 16; ++i) z[i] = 0.f;
  return z;
}

// ---------- W -> MFMA B-fragment layout ----------
// group gid = (stage*6 + t)*2 + half, stage 0..63 (k=16 each), t = n-tile 0..5.
// Lane (l31,h): col n=t*32+l31, k = stage*16 + h*8 + i.
__global__ __launch_bounds__(256) void wconv_kernel(
    const float* __restrict__ Wq, const float* __restrict__ Wk, const float* __restrict__ Wv,
    short* __restrict__ wsB)
{
  int gid = blockIdx.x * 4 + (threadIdx.x >> 6);  // 0..767
  int lane = threadIdx.x & 63;
  int l31 = lane & 31, h = lane >> 5;
  int half = gid & 1;
  int rem = gid >> 1;            // stage*6 + t
  int t = rem % 6;
  int stage = rem / 6;           // 0..63
  int n = t * 32 + l31;
  int mat = n >> 6, col = n & 63;
  const float* W = (mat == 0) ? Wq : (mat == 1) ? Wk : Wv;
  int kbase = stage * 16 + h * 8;
  U8 o;
#pragma unroll
  for (int i = 0; i < 8; ++i) {
    float f = W[(size_t)(kbase + i) * 64 + col];
    unsigned hb = f2bf_bits(f);
    if (half == 0) o.s[i] = (short)hb;
    else {
      float hf = __uint_as_float(hb << 16);
      o.s[i] = (short)f2bf_bits(f - hf);
    }
  }
  *(bf16x8*)(wsB + (size_t)gid * 512 + lane * 8) = o.v;
}

// ---------- QKV projection: 32-row blocks, 6 waves = 2 k-halves x 3 n-pairs ----------
// grid 512 (2 blocks/CU), 384 threads, launch_bounds caps VGPR for 3 waves/SIMD.
__global__ __launch_bounds__(384, 3) void proj_kernel(
    const float* __restrict__ x, const short* __restrict__ wsB,
    short* __restrict__ qh, short* __restrict__ ql,
    short* __restrict__ kh, short* __restrict__ kl,
    short* __restrict__ vth, short* __restrict__ vtl)
{
  __shared__ float Rx[6 * 64 * 17];   // k-reduce exchange: ((tp*2+t)*64+lane)*17 + r
  __shared__ float Vb[32 * 68];       // v transpose bounce

  const int tid = threadIdx.x;
  const int lane = tid & 63, w = tid >> 6;   // w 0..5
  const int l31 = lane & 31, h = lane >> 5;
  const int ksel = (w >= 3) ? 1 : 0;
  const int tp = w - ksel * 3;               // 0..2 -> n-tiles tp*2, tp*2+1
  const int row0 = blockIdx.x * 32;
  const size_t xrow = (size_t)(row0 + l31) * 1024;
  const int sbase = ksel * 32;               // stage base (k offset ksel*512)

  fx16 accP[2], accQ[2];
#pragma unroll
  for (int t = 0; t < 2; ++t) { accP[t] = fzero(); accQ[t] = fzero(); }

  float4 A0[4][2], A1[4][2];
  bf16x8 B0[4], B1[4];

#define LOADA(AB, C1)                                                   \
  {                                                                     \
    _Pragma("unroll")                                                   \
    for (int ks = 0; ks < 4; ++ks) {                                    \
      int k = ksel * 512 + (C1) * 64 + ks * 16 + h * 8;                 \
      AB[ks][0] = *(const float4*)(x + xrow + k);                       \
      AB[ks][1] = *(const float4*)(x + xrow + k + 4);                   \
    }                                                                   \
  }

#define LOADB(BB, SR)                                                   \
  {                                                                     \
    _Pragma("unroll")                                                   \
    for (int tt = 0; tt < 2; ++tt) {                                    \
      size_t g2 = ((size_t)(SR) * 6 + tp * 2 + tt) * 2;                 \
      BB[tt * 2 + 0] = *(const bf16x8*)(wsB + g2 * 512 + lane * 8);     \
      BB[tt * 2 + 1] = *(const bf16x8*)(wsB + (g2 + 1) * 512 + lane * 8);\
    }                                                                   \
  }

#define STEP(AF, BB)                                                    \
  {                                                                     \
    U8 ah, al;                                                          \
    float xf[8];                                                        \
    xf[0] = AF[0].x; xf[1] = AF[0].y; xf[2] = AF[0].z; xf[3] = AF[0].w; \
    xf[4] = AF[1].x; xf[5] = AF[1].y; xf[6] = AF[1].z; xf[7] = AF[1].w; \
    _Pragma("unroll")                                                   \
    for (int i = 0; i < 8; ++i) {                                       \
      unsigned hb = f2bf_bits(xf[i]);                                   \
      ah.s[i] = (short)hb;                                              \
      float hf = __uint_as_float(hb << 16);                             \
      al.s[i] = (short)f2bf_bits(xf[i] - hf);                           \
    }                                                                   \
    _Pragma("unroll")                                                   \
    for (int tt = 0; tt < 2; ++tt) {                                    \
      accP[tt] = mfma_bf16(ah.v, BB[tt * 2 + 0], accP[tt]);             \
      accQ[tt] = mfma_bf16(ah.v, BB[tt * 2 + 1], accQ[tt]);             \
      accQ[tt] = mfma_bf16(al.v, BB[tt * 2 + 0], accQ[tt]);             \
    }                                                                   \
  }

#define CHUNK(C, ACUR, ANEXT)                                           \
  {                                                                     \
    if ((C) < 7) LOADA(ANEXT, (C) + 1);                                 \
    STEP(ACUR[0], B0); if ((C) * 4 + 2 < 32) LOADB(B0, sbase + (C) * 4 + 2); \
    STEP(ACUR[1], B1); if ((C) * 4 + 3 < 32) LOADB(B1, sbase + (C) * 4 + 3); \
    STEP(ACUR[2], B0); if ((C) * 4 + 4 < 32) LOADB(B0, sbase + (C) * 4 + 4); \
    STEP(ACUR[3], B1); if ((C) * 4 + 5 < 32) LOADB(B1, sbase + (C) * 4 + 5); \
  }

  LOADA(A0, 0);
  LOADB(B0, sbase + 0);
  LOADB(B1, sbase + 1);
  for (int c2 = 0; c2 < 4; ++c2) {
    CHUNK(2 * c2 + 0, A0, A1);
    CHUNK(2 * c2 + 1, A1, A0);
  }
#undef CHUNK
#undef STEP
#undef LOADB
#undef LOADA

  // cross-wave k-reduction
  if (ksel == 1) {
#pragma unroll
    for (int t = 0; t < 2; ++t)
#pragma unroll
      for (int r = 0; r < 16; ++r)
        Rx[((tp * 2 + t) * 64 + lane) * 17 + r] = accP[t][r] + accQ[t][r];
  }
  __syncthreads();
  if (ksel == 0) {
#pragma unroll
    for (int t = 0; t < 2; ++t) {
      const int tg = tp * 2 + t;
      const int mat = tg >> 1;
      const int colb = (tg & 1) * 32 + l31;
      if (mat < 2) {
        short* dh = (mat == 0) ? qh : kh;
        short* dl = (mat == 0) ? ql : kl;
#pragma unroll
        for (int r = 0; r < 16; ++r) {
          float f = accP[t][r] + accQ[t][r] + Rx[(tg * 64 + lane) * 17 + r];
          int rowg = row0 + (r & 3) + 8 * (r >> 2) + 4 * h;
          unsigned hb = f2bf_bits(f);
          float hf = __uint_as_float(hb << 16);
          unsigned lb = f2bf_bits(f - hf);
          dh[(size_t)rowg * 64 + colb] = (short)hb;
          dl[(size_t)rowg * 64 + colb] = (short)lb;
        }
      } else {
#pragma unroll
        for (int r = 0; r < 16; ++r) {
          float f = accP[t][r] + accQ[t][r] + Rx[(tg * 64 + lane) * 17 + r];
          int srel = (r & 3) + 8 * (r >> 2) + 4 * h;
          Vb[srel * 68 + (tg - 4) * 32 + l31] = f;
        }
      }
    }
  }
  __syncthreads();
  if (tid < 256) {
    int d = tid >> 2, s8 = (tid & 3) * 8;
    int bb = row0 >> 11, s0 = row0 & 2047;
    U8 hv, lv;
#pragma unroll
    for (int ss = 0; ss < 8; ++ss) {
      float f = Vb[(s8 + ss) * 68 + d];
      unsigned hb = f2bf_bits(f);
      float hf = __uint_as_float(hb << 16);
      hv.s[ss] = (short)hb;
      lv.s[ss] = (short)f2bf_bits(f - hf);
    }
    size_t o = (size_t)(bb * 64 + d) * 2048 + s0 + s8;
    *(bf16x8*)(vth + o) = hv.v;
    *(bf16x8*)(vtl + o) = lv.v;
  }
}

// ---------- Flash attention: Q-tile 128 (4 waves x 32 q-cols), K-step 64 ----------
// grid 576 = 8 batches (bid%8 -> XCD pinning) x 72 chunks (<=4 K-steps each).
__global__ __launch_bounds__(256, 2) void attn_kernel(
    const short* __restrict__ qh, const short* __restrict__ ql,
    const short* __restrict__ kh, const short* __restrict__ kl,
    const short* __restrict__ vth, const short* __restrict__ vtl,
    float* __restrict__ segO, float* __restrict__ segL, float* __restrict__ segM)
{
  __shared__ short Kbuf[2][64 * 128];   // row=k-row: [hi 64 d | lo 64 d], XOR-swizzled
  __shared__ short Vbuf[2][64 * 128];   // row=d:     [hi 64 k | lo 64 k], XOR-swizzled

  const int bid = blockIdx.x;
  const int b = bid & 7;                // batch -> XCD (round-robin heuristic)
  int r = bid >> 3;                     // 0..71
  int qt = 0;
  {
    int acc = 0;
    while (r >= acc + ((qt + 2) >> 1)) { acc += (qt + 2) >> 1; ++qt; }
    r -= acc;                           // r = ch
  }
  const int ch = r;
  const int St = 2 * (qt + 1);
  const int kt0 = 4 * ch;
  int nsteps = St - kt0; if (nsteps > 4) nsteps = 4;

  const int tid = threadIdx.x;
  const int lane = tid & 63, w = tid >> 6;
  const int l31 = lane & 31, h = lane >> 5;
  const int qabs = qt * 128 + w * 32 + l31;

  // Q B-frags (hoisted): B[kk=d][col=q]
  bf16x8 qf0[4], qf1[4];
  {
    size_t qrow = ((size_t)b * 2048 + qabs) * 64;
#pragma unroll
    for (int ds = 0; ds < 4; ++ds) {
      qf0[ds] = *(const bf16x8*)(qh + qrow + ds * 16 + 8 * h);
      qf1[ds] = *(const bf16x8*)(ql + qrow + ds * 16 + 8 * h);
    }
  }

  // staging constants
  const int slot = tid & 15;
  const int half = slot >> 3;
  const int sb = (slot & 7) << 4;
  const int rbase = tid >> 4;
  const int d0 = (sb ^ ((rbase & 7) << 4)) >> 1;
  const short* ksrc = half ? kl : kh;
  const short* vsrc = half ? vtl : vth;
  const int woff = rbase * 256 + half * 128 + sb;

  fx16 accA0 = fzero(), accA1 = fzero(), accB0 = fzero(), accB1 = fzero();
  float Mrun = -3e38f, lrun = 0.f;
  const int sw = (l31 & 7) << 4;

  bf16x8 kreg[4], vreg[4];
#pragma unroll
  for (int jj = 0; jj < 4; ++jj) {
    kreg[jj] = *(const bf16x8*)(ksrc + ((size_t)b * 2048 + (size_t)kt0 * 64 + rbase + 16 * jj) * 64 + d0);
    vreg[jj] = *(const bf16x8*)(vsrc + ((size_t)(b * 64 + rbase + 16 * jj)) * 2048 + kt0 * 64 + d0);
  }
#pragma unroll
  for (int jj = 0; jj < 4; ++jj) {
    *(bf16x8*)((char*)Kbuf[0] + woff + jj * 4096) = kreg[jj];
    *(bf16x8*)((char*)Vbuf[0] + woff + jj * 4096) = vreg[jj];
  }
  __syncthreads();

  for (int it = 0; it < nsteps; ++it) {
    const int kt = kt0 + it;
    const int p = it & 1;
    const bool hasnext = (it + 1 < nsteps);
    if (hasnext) {
      int kn = kt + 1;
#pragma unroll
      for (int jj = 0; jj < 4; ++jj) {
        kreg[jj] = *(const bf16x8*)(ksrc + ((size_t)b * 2048 + (size_t)kn * 64 + rbase + 16 * jj) * 64 + d0);
        vreg[jj] = *(const bf16x8*)(vsrc + ((size_t)(b * 64 + rbase + 16 * jj)) * 2048 + kn * 64 + d0);
      }
    }

#pragma unroll
    for (int ms = 0; ms < 2; ++ms) {
      // QK^T (swapped): S^T sub-tile 32k x 32q
      fx16 stA = fzero(), stB = fzero(), stC = fzero();
      {
        const char* arow = (const char*)Kbuf[p] + (ms * 32 + l31) * 256;
        __builtin_amdgcn_s_setprio(1);
#pragma unroll
        for (int ds = 0; ds < 4; ++ds) {
          const int kb = ds * 32 + 16 * h;
          bf16x8 ah = *(const bf16x8*)(arow + (kb ^ sw));
          bf16x8 al = *(const bf16x8*)(arow + 128 + (kb ^ sw));
          stA = mfma_bf16(ah, qf0[ds], stA);
          stB = mfma_bf16(ah, qf1[ds], stB);
          stC = mfma_bf16(al, qf0[ds], stC);
        }
        __builtin_amdgcn_s_setprio(0);
      }
      float sv[16];
      const int kbase = kt * 64 + ms * 32;
      const bool diag = (kbase + 31 > qt * 128 + w * 32);   // wave-uniform
#pragma unroll
      for (int rr = 0; rr < 16; ++rr) {
        float s = (stA[rr] + stB[rr] + stC[rr]) * 0.125f;
        if (diag) {
          int ka = kbase + (rr & 3) + 8 * (rr >> 2) + 4 * h;
          if (ka > qabs) s = -3e38f;
        }
        sv[rr] = s;
      }
      float tm = sv[0];
#pragma unroll
      for (int rr = 1; rr < 16; ++rr) tm = fmaxf(tm, sv[rr]);
      tm = fmaxf(tm, __shfl_xor(tm, 32, 64));
      float Mnew = fmaxf(Mrun, tm);
      float alpha = __expf(Mrun - Mnew);
      Mrun = Mnew;
      float pvv[16]; float psum = 0.f;
#pragma unroll
      for (int rr = 0; rr < 16; ++rr) { pvv[rr] = __expf(sv[rr] - Mnew); psum += pvv[rr]; }
      psum += __shfl_xor(psum, 32, 64);
      lrun = lrun * alpha + psum;
#pragma unroll
      for (int rr = 0; rr < 16; ++rr) {
        accA0[rr] *= alpha; accA1[rr] *= alpha; accB0[rr] *= alpha; accB1[rr] *= alpha;
      }
      // P -> bf16 hi/lo packed dwords
      unsigned chv[8], clv[8];
#pragma unroll
      for (int q2 = 0; q2 < 8; ++q2) {
        unsigned c = cvt_pk_bf16(pvv[2 * q2], pvv[2 * q2 + 1]);
        chv[q2] = c;
        float f0 = __uint_as_float(c << 16);
        float f1 = __uint_as_float(c & 0xffff0000u);
        clv[q2] = cvt_pk_bf16(pvv[2 * q2] - f0, pvv[2 * q2 + 1] - f1);
      }
      // PV: O^T += V^T P^T
#pragma unroll
      for (int kp = 0; kp < 2; ++kp) {
        U8 ph, pl;
        {
          unsigned c0 = chv[4 * kp], c1 = chv[4 * kp + 1], c2 = chv[4 * kp + 2], c3 = chv[4 * kp + 3];
          unsigned x0 = (unsigned)__shfl_xor((int)c0, 32, 64);
          unsigned x1 = (unsigned)__shfl_xor((int)c1, 32, 64);
          unsigned x2 = (unsigned)__shfl_xor((int)c2, 32, 64);
          unsigned x3 = (unsigned)__shfl_xor((int)c3, 32, 64);
          ph.u[0] = h ? x2 : c0;  ph.u[1] = h ? x3 : c1;
          ph.u[2] = h ? c2 : x0;  ph.u[3] = h ? c3 : x1;
          c0 = clv[4 * kp]; c1 = clv[4 * kp + 1]; c2 = clv[4 * kp + 2]; c3 = clv[4 * kp + 3];
          x0 = (unsigned)__shfl_xor((int)c0, 32, 64);
          x1 = (unsigned)__shfl_xor((int)c1, 32, 64);
          x2 = (unsigned)__shfl_xor((int)c2, 32, 64);
          x3 = (unsigned)__shfl_xor((int)c3, 32, 64);
          pl.u[0] = h ? x2 : c0;  pl.u[1] = h ? x3 : c1;
          pl.u[2] = h ? c2 : x0;  pl.u[3] = h ? c3 : x1;
        }
        const int kbv = ms * 64 + kp * 32 + 16 * h;
        __builtin_amdgcn_s_setprio(1);
#pragma unroll
        for (int md = 0; md < 2; ++md) {
          const char* vrow = (const char*)Vbuf[p] + (md * 32 + l31) * 256;
          bf16x8 vh = *(const bf16x8*)(vrow + (kbv ^ sw));
          bf16x8 vl = *(const bf16x8*)(vrow + 128 + (kbv ^ sw));
          if (md == 0) {
            accA0 = mfma_bf16(vh, ph.v, accA0);
            accB0 = mfma_bf16(vh, pl.v, accB0);
            accB0 = mfma_bf16(vl, ph.v, accB0);
          } else {
            accA1 = mfma_bf16(vh, ph.v, accA1);
            accB1 = mfma_bf16(vh, pl.v, accB1);
            accB1 = mfma_bf16(vl, ph.v, accB1);
          }
        }
        __builtin_amdgcn_s_setprio(0);
      }
    } // ms

    if (hasnext) {
#pragma unroll
      for (int jj = 0; jj < 4; ++jj) {
        *(bf16x8*)((char*)Kbuf[p ^ 1] + woff + jj * 4096) = kreg[jj];
        *(bf16x8*)((char*)Vbuf[p ^ 1] + woff + jj * 4096) = vreg[jj];
      }
    }
    __syncthreads();
  }

  // write partials: O^T [64 d][128 q], plus l, m per q
  float* o = segO + (size_t)bid * (64 * 128);
#pragma unroll
  for (int md = 0; md < 2; ++md) {
#pragma unroll
    for (int rr = 0; rr < 16; ++rr) {
      int d = md * 32 + (rr & 3) + 8 * (rr >> 2) + 4 * h;
      float val = md ? (accA1[rr] + accB1[rr]) : (accA0[rr] + accB0[rr]);
      o[d * 128 + w * 32 + l31] = val;
    }
  }
  if (h == 0) {
    segL[(size_t)bid * 128 + w * 32 + l31] = lrun;
    segM[(size_t)bid * 128 + w * 32 + l31] = Mrun;
  }
}

// ---------- combine: merge <=8 chunks, normalize, transpose, write out ----------
__global__ __launch_bounds__(256) void combine_kernel(
    const float* __restrict__ segO, const float* __restrict__ segL,
    const float* __restrict__ segM, float* __restrict__ out)
{
  __shared__ float Sc[8][128];
  __shared__ float Linv[128];
  __shared__ float Ot[64 * 132];

  const int bq = blockIdx.x;
  const int b = bq >> 4, qt = bq & 15;
  const int nch = (qt + 2) >> 1;
  int U = 0;
  for (int i = 0; i < qt; ++i) U += (i + 2) >> 1;
  const int tid = threadIdx.x;

  if (tid < 128) {
    const int q = tid;
    float M = -3e38f;
    for (int c = 0; c < nch; ++c)
      M = fmaxf(M, segM[(size_t)(b + 8 * (U + c)) * 128 + q]);
    float L = 0.f;
    for (int c = 0; c < nch; ++c) {
      float s = __expf(segM[(size_t)(b + 8 * (U + c)) * 128 + q] - M);
      Sc[c][q] = s;
      L += s * segL[(size_t)(b + 8 * (U + c)) * 128 + q];
    }
    Linv[q] = 1.f / L;
  }
  __syncthreads();
  {
    const int dr = tid >> 5;
    const int qc = (tid & 31) * 4;
    for (int dd = dr; dd < 64; dd += 8) {
      float4 acc = {0.f, 0.f, 0.f, 0.f};
      for (int c = 0; c < nch; ++c) {
        float4 v = *(const float4*)(segO + (size_t)(b + 8 * (U + c)) * 8192 + dd * 128 + qc);
        acc.x += Sc[c][qc + 0] * v.x;
        acc.y += Sc[c][qc + 1] * v.y;
        acc.z += Sc[c][qc + 2] * v.z;
        acc.w += Sc[c][qc + 3] * v.w;
      }
      *(float4*)&Ot[dd * 132 + qc] = acc;
    }
  }
  __syncthreads();
  {
    const int q = tid >> 1, dh = (tid & 1) * 32;
    const float inv = Linv[q];
    float* dst = out + ((size_t)b * 2048 + qt * 128 + q) * 64 + dh;
#pragma unroll
    for (int i = 0; i < 8; ++i) {
      float4 o;
      o.x = Ot[(dh + 4 * i + 0) * 132 + q] * inv;
      o.y = Ot[(dh + 4 * i + 1) * 132 + q] * inv;
      o.z = Ot[(dh + 4 * i + 2) * 132 + q] * inv;
      o.w = Ot[(dh + 4 * i + 3) * 132 + q] * inv;
      *(float4*)(dst + 4 * i) = o;
    }
  }
}

// ---------- launch ----------
extern "C" void kernel_launch(void* const* d_in, const int* in_sizes, int n_in,
                              void* d_out, int out_size, void* d_ws, size_t ws_size,
                              hipStream_t stream) {
  const float* x  = (const float*)d_in[0];
  const float* Wq = (const float*)d_in[1];
  const float* Wk = (const float*)d_in[2];
  const float* Wv = (const float*)d_in[3];

  char* wsb = (char*)d_ws;
  short* wsB = (short*)(wsb + 0);                     // 786432 B
  short* qh  = (short*)(wsb + 786432);
  short* ql  = (short*)(wsb + 2883584);
  short* kh  = (short*)(wsb + 4980736);
  short* kl  = (short*)(wsb + 7077888);
  short* vth = (short*)(wsb + 9175040);
  short* vtl = (short*)(wsb + 11272192);
  float* segO = (float*)(wsb + 13369344);             // 576*8192*4 = 18874368 B
  float* segL = (float*)(wsb + 32243712);             // 294912 B
  float* segM = (float*)(wsb + 32538624);             // 294912 B

  wconv_kernel<<<192, 256, 0, stream>>>(Wq, Wk, Wv, wsB);
  proj_kernel<<<512, 384, 0, stream>>>(x, wsB, qh, ql, kh, kl, vth, vtl);
  attn_kernel<<<576, 256, 0, stream>>>(qh, ql, kh, kl, vth, vtl, segO, segL, segM);
  combine_kernel<<<128, 256, 0, stream>>>(segO, segL, segM, (float*)d_out);
}